// Round 13
// baseline (301.738 us; speedup 1.0000x reference)
//
#include <hip/hip_runtime.h>

typedef unsigned short u16;
typedef __attribute__((ext_vector_type(8))) short short8;
typedef __attribute__((ext_vector_type(8))) unsigned short ushort8;
typedef __attribute__((ext_vector_type(4))) float f32x4;
typedef __attribute__((ext_vector_type(4))) unsigned short u16x4;

#define DEV static __device__ __forceinline__

DEV u16 f2bf(float f){
    unsigned u = __float_as_uint(f);
    u += 0x7fffu + ((u >> 16) & 1u);   // round-to-nearest-even
    return (u16)(u >> 16);
}
DEV float bf2f(u16 h){ return __uint_as_float(((unsigned)h) << 16); }
DEV float sigm(float v){ return 1.f / (1.f + __expf(-v)); }

DEV f32x4 MF(short8 a, short8 b, f32x4 c){
    return __builtin_amdgcn_mfma_f32_16x16x32_bf16(a, b, c, 0, 0, 0);
}
DEV void gload16(const void* g, u16* l){
    __builtin_amdgcn_global_load_lds(
        (const __attribute__((address_space(1))) void*)g,
        (__attribute__((address_space(3))) void*)l, 16, 0, 0);
}
DEV void stage_half(const char* gp, size_t K2, u16* dst){
    gload16(gp, dst);
    gload16(gp + (K2 << 3), dst + 512);
}

#define SBAR()   asm volatile("s_barrier" ::: "memory")
#define WVM(n)   asm volatile("s_waitcnt vmcnt(" #n ")" ::: "memory")
#define WLG(n)   asm volatile("s_waitcnt lgkmcnt(" #n ")" ::: "memory")
#define SCB()    __builtin_amdgcn_sched_barrier(0)

constexpr int Bn = 8, Sn = 2048, Dn = 1024;
constexpr int CH = 128, NC = Sn / CH;          // 16 chunks along S
constexpr size_t NTOK = (size_t)Bn * Sn;       // 16384 rows

// ---------------- merged weight convert+transpose: 3 weights, 1 launch ------
// blocks [0,1024): w1 (1024x1024); [1024,2048): w2; [2048,6144): wg (2048^2)
__global__ __launch_bounds__(256) void k_wcvt3(const float* __restrict__ w1,
                                               const float* __restrict__ w2,
                                               const float* __restrict__ wg,
                                               u16* __restrict__ w1t,
                                               u16* __restrict__ w2t,
                                               u16* __restrict__ wgt)
{
    __shared__ float tile[32][33];
    int bid = blockIdx.x;
    const float* w; u16* wt; int Nd;
    if (bid < 1024){ w = w1; wt = w1t; Nd = 1024; }
    else if (bid < 2048){ w = w2; wt = w2t; Nd = 1024; bid -= 1024; }
    else { w = wg; wt = wgt; Nd = 2048; bid -= 2048; }
    int nbn = Nd / 32;
    int bk = bid / nbn, bn = bid % nbn;
    int lx = threadIdx.x & 31, ly = threadIdx.x >> 5;   // 32 x 8
    #pragma unroll
    for (int i = 0; i < 32; i += 8)
        tile[ly + i][lx] = w[(size_t)(bk * 32 + ly + i) * Nd + bn * 32 + lx];
    __syncthreads();
    #pragma unroll
    for (int i = 0; i < 32; i += 8)
        wt[(size_t)(bn * 32 + ly + i) * Nd + bk * 32 + lx] = f2bf(tile[lx][ly + i]);
}

// ---------------- cumulative average (3-phase chunked scan) -----------------
__global__ __launch_bounds__(256) void k_psum(const float* __restrict__ x,
                                              float* __restrict__ part)
{
    int bx = blockIdx.x;
    int dblk = bx & 3; bx >>= 2;
    int c = bx & (NC - 1), b = bx >> 4;
    int d = dblk * 256 + threadIdx.x;
    const float* px = x + ((size_t)b * Sn + (size_t)c * CH) * Dn + d;
    float s = 0.f;
    #pragma unroll 4
    for (int i = 0; i < CH; i++) s += px[(size_t)i * Dn];
    part[((size_t)b * NC + c) * Dn + d] = s;
}

// batched scan: 16 independent loads -> register scan -> 16 stores
__global__ __launch_bounds__(256) void k_pscan(float* part)
{
    int g = blockIdx.x * 256 + threadIdx.x;   // 8192 columns
    int b = g >> 10, d = g & 1023;
    float v[NC];
    size_t base = (size_t)b * NC * Dn + d;
    #pragma unroll
    for (int c = 0; c < NC; c++) v[c] = part[base + (size_t)c * Dn];
    float run = 0.f;
    #pragma unroll
    for (int c = 0; c < NC; c++){ float t = v[c]; v[c] = run; run += t; }
    #pragma unroll
    for (int c = 0; c < NC; c++) part[base + (size_t)c * Dn] = v[c];
}

// avg (bf16) + fused x->cat[:,0:1024] bf16 write
__global__ __launch_bounds__(256) void k_avg(const float* __restrict__ x,
                                             const float* __restrict__ part,
                                             u16* __restrict__ avg,
                                             u16* __restrict__ cat)
{
    int bx = blockIdx.x;
    int dblk = bx & 3; bx >>= 2;
    int c = bx & (NC - 1), b = bx >> 4;
    int d = dblk * 256 + threadIdx.x;
    const float* px = x   + ((size_t)b * Sn + (size_t)c * CH) * Dn + d;
    u16*         pa = avg + ((size_t)b * Sn + (size_t)c * CH) * Dn + d;
    u16*         pc = cat + ((size_t)b * Sn + (size_t)c * CH) * 2048 + d;
    float run = part[((size_t)b * NC + c) * Dn + d];
    for (int i = 0; i < CH; i++){
        float v = px[(size_t)i * Dn];
        run += v;
        int s = c * CH + i;
        pa[(size_t)i * Dn] = f2bf(run / (float)(s + 1));
        pc[(size_t)i * 2048] = f2bf(v);
    }
}

// ---------------- layernorm: avg bf16 -> ln bf16 ----------------------------
__global__ __launch_bounds__(256) void k_ln(const u16* __restrict__ avg,
                                            const float* __restrict__ g,
                                            const float* __restrict__ bta,
                                            u16* __restrict__ out)
{
    size_t row = blockIdx.x;
    int t = threadIdx.x;
    u16x4 hv = ((const u16x4*)(avg + row * Dn))[t];
    float4 v = { bf2f(hv[0]), bf2f(hv[1]), bf2f(hv[2]), bf2f(hv[3]) };
    float s = v.x + v.y + v.z + v.w;
    float q = v.x * v.x + v.y * v.y + v.z * v.z + v.w * v.w;
    #pragma unroll
    for (int o = 32; o > 0; o >>= 1){
        s += __shfl_down(s, o, 64);
        q += __shfl_down(q, o, 64);
    }
    __shared__ float rs[4], rq[4];
    __shared__ float smu, srstd;
    int wid = t >> 6, lane = t & 63;
    if (lane == 0){ rs[wid] = s; rq[wid] = q; }
    __syncthreads();
    if (t == 0){
        float S = rs[0] + rs[1] + rs[2] + rs[3];
        float Q = rq[0] + rq[1] + rq[2] + rq[3];
        float mu = S * (1.f / Dn);
        float var = Q * (1.f / Dn) - mu * mu;
        smu = mu; srstd = rsqrtf(var + 1e-6f);
    }
    __syncthreads();
    float mu = smu, rstd = srstd;
    int d0 = t * 4;
    float4 gg = ((const float4*)g)[t];
    float4 bb = ((const float4*)bta)[t];
    u16x4 o;
    o[0] = f2bf((v.x - mu) * rstd * gg.x + bb.x);
    o[1] = f2bf((v.y - mu) * rstd * gg.y + bb.y);
    o[2] = f2bf((v.z - mu) * rstd * gg.z + bb.z);
    o[3] = f2bf((v.w - mu) * rstd * gg.w + bb.w);
    *(u16x4*)(out + row * Dn + d0) = o;
}

// ---------------- 256x256x64 MFMA GEMM, 1-barrier/tile (corrected) ----------
// C = A[M,K] x Bt[N,K]^T + bias.
// r12 race fix: vmcnt is PER-WAVE, so partial WVM(N) without a barrier gives
// no cross-wave LDS guarantee. Here the tile-top wait is WVM(0) -> each wave
// drains ALL its own stage loads (only tile t's 8 remain, issued a full tile
// ago); the single SBAR then makes buf[t] collectively valid. All mid-tile
// waits are lgkmcnt on the wave's OWN ds_reads (correct semantics). Reads
// for phase p+1 issue before phase p's MFMA cluster -> LDS hides under MFMA.
// Staging t+1 -> opposite buffer; all reads of it retired (WLG(0)) before
// the preceding barrier -> write-after-read safe.
// EPI 1: ob = bf16(relu(v))                                  (inter)
// EPI 2: v += bf2f(resid); of = v; ob[2N,+N] = bf16(v)       (avg_out + cat)
// EPI 3: paired-panel gating, all-wave bf16 LDS exchange; x/avg_out from cat
template<int EPI>
__global__ __launch_bounds__(512, 2)
void k_gemm(const u16* __restrict__ A, const u16* __restrict__ Bt,
            const float* __restrict__ bias,
            float* __restrict__ of, u16* __restrict__ ob,
            const u16* __restrict__ resid,
            int M, int N, int K)
{
    __shared__ u16 smem[2][2][2][8192];   // [buf][A|B][half][128r x 64c] 128 KB

    int nbn = (EPI == 3) ? 8 : (N >> 8);
    int nwg = (M >> 8) * nbn;
    int bid = blockIdx.x;
    int swz = (bid & 7) * (nwg >> 3) + (bid >> 3);
    int bm = swz / nbn, bn = swz - bm * nbn;
    int m0 = bm << 8;
    int n0 = (EPI == 3) ? (bn << 7) : (bn << 8);

    int tid  = threadIdx.x;
    int wid  = tid >> 6, lane = tid & 63;
    int wm   = wid >> 2, wn = wid & 3;
    int fr   = lane & 15, q = lane >> 4;

    // staging addresses (source pre-swizzled per rule #21; LDS linear)
    int srow = (wid << 4) + (lane >> 3);
    int cb   = ((lane & 7) << 4) ^ (((lane >> 3) & 7) << 4);
    size_t K2 = (size_t)K * 2;
    int b1base = (EPI == 3) ? (1024 + n0) : (n0 + 128);
    const char* gA0 = (const char*)A  + (size_t)(m0 + srow) * K2 + cb;
    const char* gA1 = (const char*)A  + (size_t)(m0 + 128 + srow) * K2 + cb;
    const char* gB0 = (const char*)Bt + (size_t)(n0 + srow) * K2 + cb;
    const char* gB1 = (const char*)Bt + (size_t)(b1base + srow) * K2 + cb;
    int w16 = wid << 10;

    // fragment reads: phys elem = logical ^ ((row&7)<<3); row&7 == lane&7
    int xorE = (lane & 7) << 3;
    int cbE0 = ((q << 3) ^ xorE);
    int cbE1 = cbE0 ^ 32;
    int aOff = (wm * 64 + fr) * 64;
    int bOff = (wn * 32 + fr) * 64;

    f32x4 acc[8][4] = {};
    short8 a0f[4][2], a1f[4][2], b0f[2][2], b1f[2][2];
    int NT = K >> 6;

#define ST_A0(t) stage_half(gA0 + (size_t)(t) * 128, K2, &smem[(t)&1][0][0][w16])
#define ST_A1(t) stage_half(gA1 + (size_t)(t) * 128, K2, &smem[(t)&1][0][1][w16])
#define ST_B0(t) stage_half(gB0 + (size_t)(t) * 128, K2, &smem[(t)&1][1][0][w16])
#define ST_B1(t) stage_half(gB1 + (size_t)(t) * 128, K2, &smem[(t)&1][1][1][w16])
#define RD_A(Fr, t, half) { const u16* _p = &smem[(t)&1][0][half][0];           \
    _Pragma("unroll") for (int i = 0; i < 4; i++){                              \
        Fr[i][0] = *(const short8*)&_p[aOff + i * 1024 + cbE0];                 \
        Fr[i][1] = *(const short8*)&_p[aOff + i * 1024 + cbE1]; } }
#define RD_B(Fr, t, half) { const u16* _p = &smem[(t)&1][1][half][0];           \
    _Pragma("unroll") for (int i = 0; i < 2; i++){                              \
        Fr[i][0] = *(const short8*)&_p[bOff + i * 1024 + cbE0];                 \
        Fr[i][1] = *(const short8*)&_p[bOff + i * 1024 + cbE1]; } }
#define MMQ(Af, Bf, mo, no)                                                     \
    __builtin_amdgcn_s_setprio(1);                                              \
    _Pragma("unroll") for (int k = 0; k < 2; k++)                               \
        _Pragma("unroll") for (int mi = 0; mi < 4; mi++)                        \
            _Pragma("unroll") for (int ni = 0; ni < 2; ni++)                    \
                acc[mi+(mo)][ni+(no)] = MF(Af[mi][k], Bf[ni][k],                \
                                           acc[mi+(mo)][ni+(no)]);              \
    __builtin_amdgcn_s_setprio(0);

    // prologue: tile 0's four halves (8 loads)
    ST_A0(0); ST_B0(0); ST_A1(0); ST_B1(0);

    for (int t = 0; t + 1 < NT; ++t){
        // ---- tile top: full own-load drain + sole barrier => buf[t] valid
        WVM(0); SBAR();
        RD_A(a0f, t, 0);               // 8 ds_reads
        RD_B(b0f, t, 0);               // 4 ds_reads
        ST_A0(t + 1); ST_B0(t + 1);
        WLG(0); SCB();                 // a0f,b0f ready
        RD_A(a1f, t, 1);               // 8 ds_reads, run under Q00 MFMA
        ST_A1(t + 1);
        SCB();
        MMQ(a0f, b0f, 0, 0);
        RD_B(b1f, t, 1);               // 4 ds_reads, run under Q10 MFMA
        ST_B1(t + 1);
        SCB();
        WLG(4); SCB();                 // a1f retired (b1f may be in flight)
        MMQ(a1f, b0f, 4, 0);
        WLG(0); SCB();                 // b1f retired
        MMQ(a1f, b1f, 4, 2);
        MMQ(a0f, b1f, 0, 2);
    }
    {   // last tile: no staging
        int t = NT - 1;
        WVM(0); SBAR();
        RD_A(a0f, t, 0);
        RD_B(b0f, t, 0);
        WLG(0); SCB();
        RD_A(a1f, t, 1);
        SCB();
        MMQ(a0f, b0f, 0, 0);
        RD_B(b1f, t, 1);
        SCB();
        WLG(4); SCB();
        MMQ(a1f, b0f, 4, 0);
        WLG(0); SCB();
        MMQ(a1f, b1f, 4, 2);
        MMQ(a0f, b1f, 0, 2);
    }

    int col = lane & 15, rb = q * 4;

    if constexpr (EPI == 3){
        u16* s_in = &smem[0][0][0][0];        // [256][128] bf16, 64 KB
        u16* s_fg = s_in + 32768;             // 64 KB
        float bi[2], bf_[2];
        #pragma unroll
        for (int ni = 0; ni < 2; ni++){
            bi[ni]  = bias[n0 + wn * 32 + ni * 16 + col];
            bf_[ni] = bias[1024 + n0 + wn * 32 + ni * 16 + col];
        }
        SBAR();   // all waves done reading K-tile LDS
        #pragma unroll
        for (int mi = 0; mi < 8; mi++){
            int lrow = ((mi & 4) << 5) + wm * 64 + ((mi & 3) << 4) + rb;
            #pragma unroll
            for (int ni = 0; ni < 2; ni++){
                int c  = wn * 32 + ni * 16 + col;
                int cp = c ^ (q << 4);
                #pragma unroll
                for (int r = 0; r < 4; r++){
                    int row = lrow + r;
                    s_in[row * 128 + cp] = f2bf(sigm(acc[mi][ni][r] + bi[ni]));
                    s_fg[row * 128 + cp] = f2bf(sigm(acc[mi][ni + 2][r] + bf_[ni]));
                }
            }
        }
        WLG(0); SBAR();
        int rbase = wid * 32;
        #pragma unroll
        for (int rg = 0; rg < 8; rg++){
            int b4  = rbase + rg * 4;
            int row = b4 + (lane >> 4);
            int sw  = ((b4 >> 2) & 3) << 4;
            int c0  = (lane & 15) * 8;
            int cp  = c0 ^ sw;
            ushort8 iv = *(const ushort8*)&s_in[row * 128 + cp];
            ushort8 fv = *(const ushort8*)&s_fg[row * 128 + cp];
            size_t ga = (size_t)(m0 + row) * 2048 + n0 + c0;   // cat row base
            ushort8 xv = *(const ushort8*)&A[ga];
            ushort8 av = *(const ushort8*)&A[ga + 1024];
            size_t gb = (size_t)(m0 + row) * Dn + n0 + c0;
            float4 o0, o1;
            o0.x = bf2f(iv[0]) * bf2f(xv[0]) + bf2f(fv[0]) * bf2f(av[0]);
            o0.y = bf2f(iv[1]) * bf2f(xv[1]) + bf2f(fv[1]) * bf2f(av[1]);
            o0.z = bf2f(iv[2]) * bf2f(xv[2]) + bf2f(fv[2]) * bf2f(av[2]);
            o0.w = bf2f(iv[3]) * bf2f(xv[3]) + bf2f(fv[3]) * bf2f(av[3]);
            o1.x = bf2f(iv[4]) * bf2f(xv[4]) + bf2f(fv[4]) * bf2f(av[4]);
            o1.y = bf2f(iv[5]) * bf2f(xv[5]) + bf2f(fv[5]) * bf2f(av[5]);
            o1.z = bf2f(iv[6]) * bf2f(xv[6]) + bf2f(fv[6]) * bf2f(av[6]);
            o1.w = bf2f(iv[7]) * bf2f(xv[7]) + bf2f(fv[7]) * bf2f(av[7]);
            *(float4*)&of[gb] = o0;
            *(float4*)&of[gb + 4] = o1;
        }
        return;
    }

    #pragma unroll
    for (int mi = 0; mi < 8; mi++){
        int lrow = m0 + ((mi & 4) << 5) + wm * 64 + ((mi & 3) << 4) + rb;
        #pragma unroll
        for (int ni = 0; ni < 4; ni++){
            int gn = n0 + ((ni & 2) << 6) + wn * 32 + ((ni & 1) << 4) + col;
            float bv = bias[gn];
            #pragma unroll
            for (int r = 0; r < 4; r++){
                int gm = lrow + r;
                float v = acc[mi][ni][r] + bv;
                if constexpr (EPI == 1){
                    ob[(size_t)gm * N + gn] = f2bf(fmaxf(v, 0.f));
                } else {
                    v += bf2f(resid[(size_t)gm * N + gn]);
                    of[(size_t)gm * N + gn] = v;
                    ob[(size_t)gm * 2 * N + N + gn] = f2bf(v);
                }
            }
        }
    }
}

// ---------------- launch -----------------------------------------------------
extern "C" void kernel_launch(void* const* d_in, const int* in_sizes, int n_in,
                              void* d_out, int out_size, void* d_ws, size_t ws_size,
                              hipStream_t stream)
{
    const float* x   = (const float*)d_in[0];
    const float* w1  = (const float*)d_in[1];
    const float* b1  = (const float*)d_in[2];
    const float* w2  = (const float*)d_in[3];
    const float* b2  = (const float*)d_in[4];
    const float* lng = (const float*)d_in[5];
    const float* lnb = (const float*)d_in[6];
    const float* wg  = (const float*)d_in[7];
    const float* bg  = (const float*)d_in[8];

    float* gated   = (float*)d_out;                    // [16384,1024]
    float* avg_out = (float*)d_out + NTOK * Dn;        // [16384,1024]

    char* ws = (char*)d_ws;
    u16*   w1t   = (u16*)  (ws + (0ull   << 20));      // 2 MB
    u16*   w2t   = (u16*)  (ws + (2ull   << 20));      // 2 MB
    u16*   wgt   = (u16*)  (ws + (4ull   << 20));      // 8 MB
    float* part  = (float*)(ws + (12ull  << 20));      // 0.5 MB
    u16*   avg   = (u16*)  (ws + (16ull  << 20));      // 32 MB (bf16)
    u16*   ln    = (u16*)  (ws + (80ull  << 20));      // 32 MB
    u16*   inter = (u16*)  (ws + (112ull << 20));      // 32 MB
    u16*   cat   = (u16*)  (ws + (144ull << 20));      // 64 MB  -> total 208 MB

    // weights -> bf16 transposed [N,K] (single merged launch)
    k_wcvt3<<<dim3(6144), 256, 0, stream>>>(w1, w2, wg, w1t, w2t, wgt);

    // cumulative average (+ fused x->cat bf16)
    k_psum <<<dim3(Bn * NC * 4), 256, 0, stream>>>(x, part);
    k_pscan<<<dim3(Bn * Dn / 256), 256, 0, stream>>>(part);
    k_avg  <<<dim3(Bn * NC * 4), 256, 0, stream>>>(x, part, avg, cat);

    // LN
    k_ln<<<dim3((int)NTOK), 256, 0, stream>>>(avg, lng, lnb, ln);

    // FFN GEMMs (256x256 tiles, 512 threads)
    k_gemm<1><<<dim3((int)(NTOK / 256) * (Dn / 256)), 512, 0, stream>>>(
        ln, w1t, b1, nullptr, inter, nullptr, (int)NTOK, Dn, Dn);
    k_gemm<2><<<dim3((int)(NTOK / 256) * (Dn / 256)), 512, 0, stream>>>(
        inter, w2t, b2, avg_out, cat, avg, (int)NTOK, Dn, Dn);

    // gating GEMM, fused sigmoid-combine epilogue (writes gated directly)
    k_gemm<3><<<dim3((int)(NTOK / 256) * 8), 512, 0, stream>>>(
        cat, wgt, bg, gated, nullptr, nullptr, (int)NTOK, 2 * Dn, 2 * Dn);
}